// Round 1
// baseline (176.832 us; speedup 1.0000x reference)
//
#include <hip/hip_runtime.h>
#include <math.h>

#define B 8
#define C 64
#define HIN 224
#define WIN 224
#define PLANE (HIN*WIN)        // 50176
#define PLANE4 (PLANE/4)       // 12544
#define QUART (PLANE4/4)       // 3136
#define OH 64
#define OW 128
#define OUT_PER_BC (OH*OW)     // 8192
#define NGRID (OH*OW)          // grid points per batch in the "small" corner
#define POOLED_SIZE (B*C*OH*OW) // 4194304

// ws layout (floats):
// [0, 2048)            : partial sums [bc][quarter]
// [4096, 4096+131072)  : coords [b][8192] float2 (ix, iy)
#define WS_PARTIAL 0
#define WS_COORDS 4096

#define PI_F 3.14159265358979323846f

__device__ __forceinline__ float bilinear(const float* __restrict__ p,
                                          float ix, float iy) {
    float x0f = floorf(ix), y0f = floorf(iy);
    int x0 = (int)x0f, y0 = (int)y0f;
    float wx = ix - x0f, wy = iy - y0f;
    int x1 = min(x0 + 1, WIN - 1);
    int y1 = min(y0 + 1, HIN - 1);
    const float* r0 = p + y0 * WIN;
    const float* r1 = p + y1 * WIN;
    float v00 = r0[x0], v01 = r0[x1], v10 = r1[x0], v11 = r1[x1];
    float v0 = v00 + (v01 - v00) * wx;
    float v1 = v10 + (v11 - v10) * wx;
    return v0 + (v1 - v0) * wy;
}

// ---------------- K1: gap partial sums + constant-region fill ----------------
// The constant region (pooled h>=16 or w>=32) only depends on x and l_t, so
// its 15.7 MB of writes overlap this kernel's 102.8 MB of reads instead of
// sitting behind the coords dependency.
__global__ __launch_bounds__(256) void k1_gap_fill(const float* __restrict__ x,
                                                   const float* __restrict__ l_t,
                                                   float* __restrict__ ws,
                                                   float* __restrict__ out) {
    int blk = blockIdx.x;          // bc*4 + q
    int bc  = blk >> 2, q = blk & 3;
    int b   = bc >> 6;
    int tid = threadIdx.x;

    const float4* p = (const float4*)x + (size_t)bc * PLANE4 + q * QUART;
    float s = 0.f;
#pragma unroll
    for (int k = 0; k < 12; ++k) {
        float4 v = p[tid + k * 256];
        s += (v.x + v.y) + (v.z + v.w);
    }
    if (tid < QUART - 12 * 256) {  // remainder: 64 float4s
        float4 v = p[tid + 12 * 256];
        s += (v.x + v.y) + (v.z + v.w);
    }

    // Constant-region sample: grid == (0,0) + l_t_prev[b] everywhere outside
    // the top-left 64x128 fine-grid corner -> after 4x4 pooling, all outputs
    // with h>=16 or w>=32 equal ONE bilinear sample.
    const float* plane = x + (size_t)bc * PLANE;
    float gx = l_t[b * 2 + 0], gy = l_t[b * 2 + 1];
    float ixc = fminf(fmaxf(((gx + 1.f) * (float)WIN - 1.f) * 0.5f, 0.f), (float)(WIN - 1));
    float iyc = fminf(fmaxf(((gy + 1.f) * (float)HIN - 1.f) * 0.5f, 0.f), (float)(HIN - 1));
    float vc = bilinear(plane, ixc, iyc);   // uniform addresses across wave: 1 txn
    float4 vc4 = make_float4(vc, vc, vc, vc);

    float4* o4 = (float4*)(out + (size_t)bc * OUT_PER_BC);
    if (q == 0) {
        // oi in [0,2048): rows h=0..15; const part is w in [32,128) -> f4 cols 8..31
#pragma unroll
        for (int k = 0; k < 2; ++k) {
            int f4i = tid + k * 256;
            if (f4i < 384) {
                int row = f4i / 24;
                int c4  = f4i - row * 24 + 8;
                o4[row * 32 + c4] = vc4;
            }
        }
    } else {
        // oi in [q*2048,(q+1)*2048): h>=16, fully constant. 512 float4s.
        o4[q * 512 + tid]       = vc4;
        o4[q * 512 + 256 + tid] = vc4;
    }

    // wave (64-lane) reduce, then cross-wave via LDS
    for (int off = 32; off; off >>= 1) s += __shfl_down(s, off, 64);
    __shared__ float lds[4];
    if ((tid & 63) == 0) lds[tid >> 6] = s;
    __syncthreads();
    if (tid == 0) ws[WS_PARTIAL + blk] = lds[0] + lds[1] + lds[2] + lds[3];
}

// ---------------- K2: fused tiny-MLP + coordinate table ----------------
// Each block redundantly recomputes the MLP for its batch (trivial: 64x32+32x2
// MACs) -> removes the single-block MLP dispatch that idled the whole GPU.
__global__ __launch_bounds__(256) void k2_coords(const float* __restrict__ w1,
                                                 const float* __restrict__ b1,
                                                 const float* __restrict__ w2,
                                                 const float* __restrict__ b2,
                                                 const float* __restrict__ l_t,
                                                 const float* __restrict__ ws,
                                                 float* __restrict__ out_weight,
                                                 float2* __restrict__ coords) {
    int tid = threadIdx.x;
    int blk = blockIdx.x;          // 256 blocks, 32 per batch
    int b   = blk >> 5;

    __shared__ float branch[C];
    __shared__ float hidden[32];
    __shared__ float wpair[2];

    if (tid < C) {
        const float* pp = ws + WS_PARTIAL + (b * C + tid) * 4;
        branch[tid] = (pp[0] + pp[1] + pp[2] + pp[3]) * (1.0f / PLANE);
    }
    __syncthreads();
    if (tid < 32) {
        float h = b1[tid];
        for (int c = 0; c < C; ++c) h += branch[c] * w1[c * 32 + tid];
        hidden[tid] = h > 0.f ? h : 0.f;
    }
    __syncthreads();
    if (tid < 2) {
        float sacc = b2[tid];
        for (int m = 0; m < 32; ++m) sacc += hidden[m] * w2[m * 2 + tid];
        float wv = 1.f / (1.f + expf(-sacc));
        wpair[tid] = wv;
        if ((blk & 31) == 0) out_weight[b * 2 + tid] = wv;
    }
    __syncthreads();

    float w0  = wpair[0];
    float w1v = wpair[1];
    float lo = logf(w0 * 0.01f);           // log(weight0 * R_MIN)
    float hi = logf(w1v * 0.6f);           // log(weight1 * R_MAX)

    int p   = blk * 256 + tid;             // [0, 65536)
    int rem = p & 8191;
    int i = rem >> 7;     // row (H dim), 0..63
    int j = rem & 127;    // col (W dim), 0..127
    float xg = (float)(i - 32) * (1.f / 32.f);
    float yg = (float)(j - 64) * (1.f / 64.f);
    float rr = sqrtf(xg * xg + yg * yg);
    float logr = logf(fmaxf(rr, 1e-12f));
    float r = 64.f * (logr - lo) / (hi - lo);
    float a = atan2f(yg, xg);
    if (!(a > 0.f)) a = 2.f * PI_F + a;
    float t = 0.5f * a * 64.f / PI_F;
    float gxv = t * (1.f / 32.f) - 1.f + l_t[b * 2 + 0];
    float gyv = r * (1.f / 32.f) - 1.f + l_t[b * 2 + 1];
    float ix = ((gxv + 1.f) * (float)WIN - 1.f) * 0.5f;
    float iy = ((gyv + 1.f) * (float)HIN - 1.f) * 0.5f;
    ix = fminf(fmaxf(ix, 0.f), (float)(WIN - 1));
    iy = fminf(fmaxf(iy, 0.f), (float)(HIN - 1));
    coords[p] = make_float2(ix, iy);
}

// ---------------- K3: corner bilinear sample + 4x4 avg pool ----------------
// One thread per HALF pooled output (2 fine rows x 4 fine cols = 8 samples),
// pair-reduced with one shfl. Grid 2048 blocks -> 8 blocks/CU -> 32 waves/CU
// (was 8): 4x the latency-hiding for the scattered gathers.
__global__ __launch_bounds__(256) void k3_corner(const float* __restrict__ x,
                                                 const float2* __restrict__ coords,
                                                 float* __restrict__ out) {
    int blk = blockIdx.x;          // 0..2047 = bc*4 + q
    int bc  = blk >> 2, q = blk & 3;
    int b   = bc >> 6;
    int tid = threadIdx.x;

    int out_local = tid >> 1;      // 0..127
    int half      = tid & 1;
    int h = q * 4 + (out_local >> 5);   // pooled row 0..15
    int w = out_local & 31;             // pooled col 0..31

    const float*  plane = x + (size_t)bc * PLANE;
    const float2* cb    = coords + b * NGRID;

    float acc = 0.f;
#pragma unroll
    for (int fi2 = 0; fi2 < 2; ++fi2) {
        int fi = 4 * h + 2 * half + fi2;       // fine row
        const float2* cr = cb + fi * 128 + 4 * w;
#pragma unroll
        for (int dj = 0; dj < 4; ++dj) {
            float2 cxy = cr[dj];
            acc += bilinear(plane, cxy.x, cxy.y);
        }
    }
    acc += __shfl_xor(acc, 1, 64);
    if (half == 0) out[(size_t)bc * OUT_PER_BC + h * 128 + w] = acc * (1.f / 16.f);
}

extern "C" void kernel_launch(void* const* d_in, const int* in_sizes, int n_in,
                              void* d_out, int out_size, void* d_ws, size_t ws_size,
                              hipStream_t stream) {
    const float* x   = (const float*)d_in[0];
    const float* l_t = (const float*)d_in[1];
    const float* w1  = (const float*)d_in[2];
    const float* b1  = (const float*)d_in[3];
    const float* w2  = (const float*)d_in[4];
    const float* b2  = (const float*)d_in[5];
    float* out = (float*)d_out;
    float* ws  = (float*)d_ws;

    k1_gap_fill<<<dim3(B * C * 4), dim3(256), 0, stream>>>(x, l_t, ws, out);
    k2_coords<<<dim3(NGRID * B / 256), dim3(256), 0, stream>>>(
        w1, b1, w2, b2, l_t, ws, out + POOLED_SIZE, (float2*)(ws + WS_COORDS));
    k3_corner<<<dim3(B * C * 4), dim3(256), 0, stream>>>(
        x, (const float2*)(ws + WS_COORDS), out);
}